// Round 10
// baseline (202.466 us; speedup 1.0000x reference)
//
#include <hip/hip_runtime.h>
#include <hip/hip_bf16.h>

#define EPSV 1e-5f
#define TW 4    // waves per block
#define TPW 8   // points per wave-tile
#define SPD 76  // padded LDS row stride (shorts)
#define WPD 68  // padded prep LDS row stride (floats; 16B-aligned, conflict-free)

typedef __attribute__((ext_vector_type(8))) short s8v;
typedef __attribute__((ext_vector_type(8))) unsigned short u8v;
typedef __attribute__((ext_vector_type(4))) unsigned short u4v;
typedef __attribute__((ext_vector_type(4))) float f4v;

struct InP {
  const float *points, *features; const int* gidx;
  const float *Wq,*bq,*Wk,*bk,*Wv,*bv,*Wp,*b_p;
  const float *bnp_g,*bnp_b,*bnp_m,*bnp_v;
  const float *Wg1,*bg1,*bng_g,*bng_b,*bng_m,*bng_v;
  const float *Wg2,*bg2,*Wo,*bo;
  float* out; int N;
};
// Workspace layouts (R14 -- PERMUTED so MFMA C-frags store wide and the
// main gather loads wide; producer/consumer co-designed):
//   qW1: N rows x 64 shorts; element (row, col=nt*16+cl) at row*64 + cl*4 + nt
//   kvT: N rows x 128 shorts; kW1 elem (row, nt*16+cl) at row*128 + cl*8 + nt
//        v elem (row, nt*16+cl) at row*128 + cl*8 + 4 + nt
struct WS {
  unsigned short *qW1;                               // N x 64 bf16 (q@W1F + b1F), permuted
  unsigned short *kvT;                               // N x 128 bf16 (kW1|v interleaved), permuted
  unsigned short *WAf, *Wkf, *Wvf, *W1f, *W2f, *Wof; // 8 frags x 64 lanes x 8 bf16
  unsigned short *Wpf;                               // 4 frags x 64 x 8
  float *bq1F, *bpF, *bk1F;                          // 64 fp32 each
};

__device__ __forceinline__ unsigned short f2bf(float x){
  __hip_bfloat16 h = __float2bfloat16(x);
  unsigned short u; __builtin_memcpy(&u, &h, 2); return u;
}
__device__ __forceinline__ float bf2f(unsigned short s){
  union{unsigned u; float f;} c; c.u = ((unsigned)s) << 16; return c.f;
}
__device__ __forceinline__ unsigned pk2(float x, float y){
  __hip_bfloat162 h = __float22bfloat162_rn(make_float2(x, y));
  unsigned u; __builtin_memcpy(&u, &h, 4); return u;
}
__device__ __forceinline__ s8v pack8(f4v x0, f4v x1){
  s8v r;
  ((unsigned*)&r)[0] = pk2(x0[0], x0[1]);
  ((unsigned*)&r)[1] = pk2(x0[2], x0[3]);
  ((unsigned*)&r)[2] = pk2(x1[0], x1[1]);
  ((unsigned*)&r)[3] = pk2(x1[2], x1[3]);
  return r;
}

// ---------------- prep: BN folds + fused k@W1 + B-fragment swizzles -------
// R19: Wg1/Wq/Wk staged in LDS (padded WPD) -- dots run at LDS latency.
__global__ void __launch_bounds__(256) prep_kernel(InP P, WS W){
  __shared__ __align__(16) float sWg1[64*WPD];
  __shared__ __align__(16) float sWq [64*WPD];
  __shared__ __align__(16) float sWk [64*WPD];
  const int tid = threadIdx.x;
  {
    int r = tid >> 2, c0 = (tid & 3) * 16;   // 4 threads per 64-float row
    const f4v* g1 = (const f4v*)(P.Wg1 + r*64 + c0);
    const f4v* gq = (const f4v*)(P.Wq  + r*64 + c0);
    const f4v* gk = (const f4v*)(P.Wk  + r*64 + c0);
    f4v* d1 = (f4v*)(sWg1 + r*WPD + c0);
    f4v* dq = (f4v*)(sWq  + r*WPD + c0);
    f4v* dk = (f4v*)(sWk  + r*WPD + c0);
    #pragma unroll
    for (int u = 0; u < 4; u++){ d1[u] = g1[u]; dq[u] = gq[u]; dk[u] = gk[u]; }
  }
  __syncthreads();

  const int g = blockIdx.x*256 + tid;           // 0..4095
  const int e = g >> 3, j = g & 7;              // e < 512
  const int f = e >> 6, L = e & 63;
  const int ks = f & 1, nt = f >> 1;
  const int n = nt*16 + (L & 15);
  const int k = ks*32 + ((L >> 4) << 3) + j;
  const float sg = P.bng_g[n] * rsqrtf(P.bng_v[n] + EPSV);
  W.W1f[e*8+j] = f2bf(sWg1[k*WPD+n] * sg);
  W.W2f[e*8+j] = f2bf(P.Wg2[k*64+n]);
  W.Wof[e*8+j] = f2bf(P.Wo [k*64+n]);
  W.Wvf[e*8+j] = f2bf(P.Wv [k*64+n]);
  float acc = 0.f, acck = 0.f;
  #pragma unroll 8
  for (int d = 0; d < 64; d++){
    float w1 = sWg1[d*WPD+n];
    acc  += sWq[k*WPD+d] * w1;
    acck += sWk[k*WPD+d] * w1;
  }
  W.WAf[e*8+j] = f2bf(acc  * sg);   // Wq@W1F (BN-scaled)
  W.Wkf[e*8+j] = f2bf(acck * sg);   // Wk@W1F (BN-scaled) -- fused
  if (g < 2048){
    int ep = g >> 3;  // 0..255
    int ntp = ep >> 6, Lp = ep & 63;
    int np_ = ntp*16 + (Lp & 15);
    int kp = ((Lp >> 4) << 3) + j;
    float sp = P.bnp_g[np_] * rsqrtf(P.bnp_v[np_] + EPSV);
    W.Wpf[ep*8+j] = f2bf(kp < 3 ? P.Wp[kp*64+np_]*sp : 0.f);
  }
  if (g < 64){
    float sgt = P.bng_g[g] * rsqrtf(P.bng_v[g] + EPSV);
    float spt = P.bnp_g[g] * rsqrtf(P.bnp_v[g] + EPSV);
    float acc2 = 0.f, acck2 = 0.f;
    for (int d = 0; d < 64; d++){
      float w1 = sWg1[d*WPD+g];
      acc2  += P.bq[d] * w1;
      acck2 += P.bk[d] * w1;
    }
    // qW1 bias carries ALL of b1F (bg1 + BN offset); kW1 bias only bk@W1F
    W.bq1F[g] = acc2*sgt + P.bg1[g]*sgt + P.bng_b[g] - P.bng_m[g]*sgt;
    W.bk1F[g] = acck2*sgt;
    W.bpF[g]  = P.b_p[g]*spt + P.bnp_b[g] - P.bnp_m[g]*spt;
  }
}

// ---- qkv: qW1 = f@(Wq@W1F)+bq1F ; kvT = [f@(Wk@W1F)+bk1F | f@Wv+bv] ----
// R14: wide permuted stores -- coalesced, 256B contiguous per 16 lanes.
__global__ void __launch_bounds__(256) qkv_kernel(InP P, WS W){
  const int tid = threadIdx.x;
  const int wid = tid >> 6, l = tid & 63;
  const int cl = l & 15, q = l >> 4;
  const int TILES = (P.N + 15) >> 4;
  const int task = blockIdx.x * TW + wid;
  if (task >= TILES) return;
  const int i0 = task * 16;
  int row = i0 + cl; if (row > P.N - 1) row = P.N - 1;
  const float* fr = P.features + (size_t)row*64 + q*8;
  f4v x0 = *(const f4v*)fr;
  f4v x1 = *(const f4v*)(fr + 4);
  s8v fa0 = pack8(x0, x1);
  x0 = *(const f4v*)(fr + 32);
  x1 = *(const f4v*)(fr + 36);
  s8v fa1 = pack8(x0, x1);

  auto comp = [&](const unsigned short* Bf_, const float* biasPtr, f4v* c){
    const s8v* Bf = (const s8v*)Bf_;
    #pragma unroll
    for (int nt = 0; nt < 4; nt++){
      float bn = biasPtr[nt*16 + cl];
      f4v ci = { bn, bn, bn, bn };
      c[nt] = __builtin_amdgcn_mfma_f32_16x16x32_bf16(fa0, Bf[(2*nt+0)*64 + l], ci, 0, 0, 0);
      c[nt] = __builtin_amdgcn_mfma_f32_16x16x32_bf16(fa1, Bf[(2*nt+1)*64 + l], c[nt], 0, 0, 0);
    }
  };
  f4v qc[4], kc[4], vc[4];
  comp(W.WAf, W.bq1F, qc);
  comp(W.Wkf, W.bk1F, kc);
  comp(W.Wvf, P.bv,   vc);

  #pragma unroll
  for (int r = 0; r < 4; r++){
    int rg = i0 + q*4 + r;
    if (rg < P.N){
      u4v qv;
      qv[0] = f2bf(qc[0][r]); qv[1] = f2bf(qc[1][r]);
      qv[2] = f2bf(qc[2][r]); qv[3] = f2bf(qc[3][r]);
      *(u4v*)(W.qW1 + (size_t)rg*64 + cl*4) = qv;
      u8v kv;
      kv[0] = f2bf(kc[0][r]); kv[1] = f2bf(kc[1][r]);
      kv[2] = f2bf(kc[2][r]); kv[3] = f2bf(kc[3][r]);
      kv[4] = f2bf(vc[0][r]); kv[5] = f2bf(vc[1][r]);
      kv[6] = f2bf(vc[2][r]); kv[7] = f2bf(vc[3][r]);
      *(u8v*)(W.kvT + (size_t)rg*128 + cl*8) = kv;
    }
  }
}

// ---------------- main: PAIRED points (R20) -------------------------------
// EXONERATED (R11-R19): gather shape/issue/depth, occupancy x2, forced
// bounds, nt hints, fusion; non-main ~119us = harness reset dispatches.
// R20: the last untested lever -- IN-WAVE CHAIN ILP. Each point's
// p->Sp->T->Sp->H->softmax chain ran serially with lgkmcnt drains at each
// boundary and nothing else to issue (waves ~75% stall, lockstep waits).
// Now points (pt, pt+1) run INTERLEAVED: parity double-buffer gives
// disjoint Sp rows, so both points' writes burst together, both reads
// burst together -- ONE lgkmcnt drain per boundary for TWO points, and
// the scheduler fills A's stalls with B's independent instructions.
// VGPR ~76 -> ~120-140 (kv/pc/hc/prefetch x2); launch_bounds stays (256,2).
// Spill tripwire: WRITE_SIZE must stay 12.5MB.
__global__ void __launch_bounds__(256, 2) main_kernel(InP P, WS W){
  __shared__ __align__(16) unsigned short Sp[TW][2][16*SPD];
  __shared__ __align__(16) unsigned short PreB[TW][TPW*SPD];
  __shared__ __align__(16) int sI[TW][TPW*16];
  __shared__ __align__(16) unsigned short sW1[8*64*8];
  __shared__ __align__(16) unsigned short sW2[8*64*8];
  const int tid = threadIdx.x;
  const int wid = tid >> 6, l = tid & 63;
  const int cl = l & 15, q = l >> 4;
  const int TILES = (P.N + TPW - 1) / TPW;
  const int task = blockIdx.x * TW + wid;

  // cooperative W1F/W2F staging (before any early return; barrier safety)
  {
    const int4* s1 = (const int4*)W.W1f;
    const int4* s2 = (const int4*)W.W2f;
    ((int4*)sW1)[tid]       = s1[tid];
    ((int4*)sW1)[tid + 256] = s1[tid + 256];
    ((int4*)sW2)[tid]       = s2[tid];
    ((int4*)sW2)[tid + 256] = s2[tid + 256];
  }
  __syncthreads();
  if (task >= TILES) return;
  const int i0 = task * TPW;
  unsigned short* PreBw = PreB[wid];
  int* sIw = sI[wid];
  const s8v* W1s = (const s8v*)sW1;
  const s8v* W2s = (const s8v*)sW2;

  // neighbor-index stage (TPW*16 = 128 ints per tile, 2/lane)
  {
    long base = (long)i0*16 + l*2;
    long maxb = (long)P.N*16 - 2;
    if (base > maxb) base = maxb;
    int2 gi = *(const int2*)(P.gidx + base);
    *(int2*)&sIw[l*2] = gi;
  }

  s8v wpf[4];
  {
    const s8v* Wpp = (const s8v*)W.Wpf;
    #pragma unroll
    for (int f = 0; f < 4; f++) wpf[f] = Wpp[f*64 + l];
  }
  float bp4[4], b24[4];
  #pragma unroll
  for (int nt = 0; nt < 4; nt++){ bp4[nt] = W.bpF[nt*16 + cl]; b24[nt] = P.bg2[nt*16 + cl]; }

  // ---- prologue prefetch: A = pt0, B = pt1 (xyz, center, qW1 row)
  float nAgx=0.f,nAgy=0.f,nAgz=0.f, nBgx=0.f,nBgy=0.f,nBgz=0.f;
  {
    if (l < 16){
      int na = sIw[cl];        const float* ga = P.points + (size_t)na*3;
      nAgx=ga[0]; nAgy=ga[1]; nAgz=ga[2];
      int nb = sIw[16 + cl];   const float* gb = P.points + (size_t)nb*3;
      nBgx=gb[0]; nBgy=gb[1]; nBgz=gb[2];
    }
  }
  float nAcx = P.points[(size_t)i0*3+0], nAcy = P.points[(size_t)i0*3+1], nAcz = P.points[(size_t)i0*3+2];
  float nBcx = P.points[(size_t)(i0+1)*3+0], nBcy = P.points[(size_t)(i0+1)*3+1], nBcz = P.points[(size_t)(i0+1)*3+2];
  float nAq0,nAq1,nAq2,nAq3, nBq0,nBq1,nBq2,nBq3;
  {
    u4v qa = *(const u4v*)(W.qW1 + (size_t)i0*64 + cl*4);
    nAq0=bf2f(qa[0]); nAq1=bf2f(qa[1]); nAq2=bf2f(qa[2]); nAq3=bf2f(qa[3]);
    u4v qb = *(const u4v*)(W.qW1 + (size_t)(i0+1)*64 + cl*4);
    nBq0=bf2f(qb[0]); nBq1=bf2f(qb[1]); nBq2=bf2f(qb[2]); nBq3=bf2f(qb[3]);
  }

  int zro = 0;  // opaque zero (defeats LICM of the sW1/sW2 frag reads)

  #pragma unroll 1
  for (int pt = 0; pt < TPW; pt += 2){
    asm volatile("" : "+v"(zro));
    unsigned short* SpA = Sp[wid][0];
    unsigned short* SpB = Sp[wid][1];
    // rotate prefetch -> current
    float gxA=nAgx, gyA=nAgy, gzA=nAgz, cxA=nAcx, cyA=nAcy, czA=nAcz;
    float gxB=nBgx, gyB=nBgy, gzB=nBgz, cxB=nBcx, cyB=nBcy, czB=nBcz;
    float qA4[4] = { nAq0, nAq1, nAq2, nAq3 };
    float qB4[4] = { nBq0, nBq1, nBq2, nBq3 };
    const bool vA = (i0 + pt     < P.N);
    const bool vB = (i0 + pt + 1 < P.N);

    // 1. gathers for BOTH points (8 x 16B in flight together)
    u8v kvA[4], kvB[4];
    {
      int4 via = *(const int4*)&sIw[pt*16 + q*4];
      int4 vib = *(const int4*)&sIw[(pt+1)*16 + q*4];
      #pragma unroll
      for (int r = 0; r < 4; r++){
        kvA[r] = *(const u8v*)(W.kvT + (size_t)via[r]*128 + cl*8);
        kvB[r] = *(const u8v*)(W.kvT + (size_t)vib[r]*128 + cl*8);
      }
    }

    // 2. GEMM0 both; one LDS write burst (32 scalar writes)
    f4v pcA[4], pcB[4];
    {
      s8v apA, apB;
      ((unsigned*)&apA)[0] = pk2(gxA-cxA, gyA-cyA);
      ((unsigned*)&apA)[1] = pk2(gzA-czA, 0.f);
      ((unsigned*)&apA)[2] = 0u; ((unsigned*)&apA)[3] = 0u;
      ((unsigned*)&apB)[0] = pk2(gxB-cxB, gyB-cyB);
      ((unsigned*)&apB)[1] = pk2(gzB-czB, 0.f);
      ((unsigned*)&apB)[2] = 0u; ((unsigned*)&apB)[3] = 0u;
      #pragma unroll
      for (int nt = 0; nt < 4; nt++){
        f4v ci = { bp4[nt], bp4[nt], bp4[nt], bp4[nt] };
        pcA[nt] = __builtin_amdgcn_mfma_f32_16x16x32_bf16(apA, wpf[nt], ci, 0, 0, 0);
        pcB[nt] = __builtin_amdgcn_mfma_f32_16x16x32_bf16(apB, wpf[nt], ci, 0, 0, 0);
      }
      #pragma unroll
      for (int nt = 0; nt < 4; nt++){
        #pragma unroll
        for (int r = 0; r < 4; r++){
          pcA[nt][r] = fmaxf(pcA[nt][r], 0.f);
          pcB[nt][r] = fmaxf(pcB[nt][r], 0.f);
          SpA[(q*4+r)*SPD + nt*16 + cl] = f2bf(pcA[nt][r]);
          SpB[(q*4+r)*SPD + nt*16 + cl] = f2bf(pcB[nt][r]);
        }
      }
    }

    // 3. prefetch pt+2 (A-regs) / pt+3 (B-regs); wraps harmlessly
    {
      int np2 = (pt + 2) & (TPW-1), np3 = (pt + 3) & (TPW-1);
      if (l < 16){
        int na = sIw[np2*16 + cl]; const float* ga = P.points + (size_t)na*3;
        nAgx=ga[0]; nAgy=ga[1]; nAgz=ga[2];
        int nb = sIw[np3*16 + cl]; const float* gb = P.points + (size_t)nb*3;
        nBgx=gb[0]; nBgy=gb[1]; nBgz=gb[2];
      }
      int iA = i0 + np2; if (iA > P.N - 1) iA = P.N - 1;
      int iB = i0 + np3; if (iB > P.N - 1) iB = P.N - 1;
      nAcx = P.points[(size_t)iA*3+0]; nAcy = P.points[(size_t)iA*3+1]; nAcz = P.points[(size_t)iA*3+2];
      nBcx = P.points[(size_t)iB*3+0]; nBcy = P.points[(size_t)iB*3+1]; nBcz = P.points[(size_t)iB*3+2];
      u4v qa = *(const u4v*)(W.qW1 + (size_t)iA*64 + cl*4);
      nAq0=bf2f(qa[0]); nAq1=bf2f(qa[1]); nAq2=bf2f(qa[2]); nAq3=bf2f(qa[3]);
      u4v qb = *(const u4v*)(W.qW1 + (size_t)iB*64 + cl*4);
      nBq0=bf2f(qb[0]); nBq1=bf2f(qb[1]); nBq2=bf2f(qb[2]); nBq3=bf2f(qb[3]);
    }

    // 4. read-back burst: both points' A-frags (one lgkmcnt drain)
    s8v afA0 = *(const s8v*)&SpA[cl*SPD + q*8];
    s8v afA1 = *(const s8v*)&SpA[cl*SPD + 32 + q*8];
    s8v afB0 = *(const s8v*)&SpB[cl*SPD + q*8];
    s8v afB1 = *(const s8v*)&SpB[cl*SPD + 32 + q*8];

    // 5. GEMM1 both: T = relu(p @ W1F + (qW1 - kW1))
    f4v tcA[4], tcB[4];
    #pragma unroll
    for (int nt = 0; nt < 4; nt++){
      f4v ciA = { qA4[nt] - bf2f((unsigned short)kvA[0][nt]),
                  qA4[nt] - bf2f((unsigned short)kvA[1][nt]),
                  qA4[nt] - bf2f((unsigned short)kvA[2][nt]),
                  qA4[nt] - bf2f((unsigned short)kvA[3][nt]) };
      f4v ciB = { qB4[nt] - bf2f((unsigned short)kvB[0][nt]),
                  qB4[nt] - bf2f((unsigned short)kvB[1][nt]),
                  qB4[nt] - bf2f((unsigned short)kvB[2][nt]),
                  qB4[nt] - bf2f((unsigned short)kvB[3][nt]) };
      s8v b0 = W1s[(2*nt+0)*64 + l + zro];
      s8v b1 = W1s[(2*nt+1)*64 + l + zro];
      tcA[nt] = __builtin_amdgcn_mfma_f32_16x16x32_bf16(afA0, b0, ciA, 0, 0, 0);
      tcA[nt] = __builtin_amdgcn_mfma_f32_16x16x32_bf16(afA1, b1, tcA[nt], 0, 0, 0);
      tcB[nt] = __builtin_amdgcn_mfma_f32_16x16x32_bf16(afB0, b0, ciB, 0, 0, 0);
      tcB[nt] = __builtin_amdgcn_mfma_f32_16x16x32_bf16(afB1, b1, tcB[nt], 0, 0, 0);
      #pragma unroll
      for (int r = 0; r < 4; r++){
        tcA[nt][r] = fmaxf(tcA[nt][r], 0.f);
        tcB[nt][r] = fmaxf(tcB[nt][r], 0.f);
      }
    }

    // 6. T write burst, read burst (one drain for both points)
    #pragma unroll
    for (int nt = 0; nt < 4; nt++)
      #pragma unroll
      for (int r = 0; r < 4; r++){
        SpA[(q*4+r)*SPD + nt*16 + cl] = f2bf(tcA[nt][r]);
        SpB[(q*4+r)*SPD + nt*16 + cl] = f2bf(tcB[nt][r]);
      }
    s8v tfA0 = *(const s8v*)&SpA[cl*SPD + q*8];
    s8v tfA1 = *(const s8v*)&SpA[cl*SPD + 32 + q*8];
    s8v tfB0 = *(const s8v*)&SpB[cl*SPD + q*8];
    s8v tfB1 = *(const s8v*)&SpB[cl*SPD + 32 + q*8];

    // 7. GEMM2 both
    f4v hcA[4], hcB[4];
    #pragma unroll
    for (int nt = 0; nt < 4; nt++){
      f4v ci = { b24[nt], b24[nt], b24[nt], b24[nt] };
      s8v b0 = W2s[(2*nt+0)*64 + l + zro];
      s8v b1 = W2s[(2*nt+1)*64 + l + zro];
      hcA[nt] = __builtin_amdgcn_mfma_f32_16x16x32_bf16(tfA0, b0, ci, 0, 0, 0);
      hcA[nt] = __builtin_amdgcn_mfma_f32_16x16x32_bf16(tfA1, b1, hcA[nt], 0, 0, 0);
      hcB[nt] = __builtin_amdgcn_mfma_f32_16x16x32_bf16(tfB0, b0, ci, 0, 0, 0);
      hcB[nt] = __builtin_amdgcn_mfma_f32_16x16x32_bf16(tfB1, b1, hcB[nt], 0, 0, 0);
    }

    // 8. softmax + weighted sum, both points
    float preA[4], preB4[4];
    #pragma unroll
    for (int nt = 0; nt < 4; nt++){
      float sA = 0.f, aA = 0.f, sB = 0.f, aB = 0.f;
      #pragma unroll
      for (int r = 0; r < 4; r++){
        float eA = __expf(hcA[nt][r]);
        sA += eA;
        aA = fmaf(eA, bf2f((unsigned short)kvA[r][4+nt]) + pcA[nt][r], aA);
        float eB = __expf(hcB[nt][r]);
        sB += eB;
        aB = fmaf(eB, bf2f((unsigned short)kvB[r][4+nt]) + pcB[nt][r], aB);
      }
      sA += __shfl_xor(sA, 16, 64); sB += __shfl_xor(sB, 16, 64);
      sA += __shfl_xor(sA, 32, 64); sB += __shfl_xor(sB, 32, 64);
      aA += __shfl_xor(aA, 16, 64); aB += __shfl_xor(aB, 16, 64);
      aA += __shfl_xor(aA, 32, 64); aB += __shfl_xor(aB, 32, 64);
      preA[nt]  = aA * __builtin_amdgcn_rcpf(sA);
      preB4[nt] = aB * __builtin_amdgcn_rcpf(sB);
    }
    if (vA){
      float sa = (l & 16) ? preA[1] : preA[0];
      float sb = (l & 16) ? preA[3] : preA[2];
      PreBw[pt*SPD + l] = f2bf((l & 32) ? sb : sa);
    }
    if (vB){
      float sa = (l & 16) ? preB4[1] : preB4[0];
      float sb = (l & 16) ? preB4[3] : preB4[2];
      PreBw[(pt+1)*SPD + l] = f2bf((l & 32) ? sb : sa);
    }
  }

  // inline epilogue: out rows = PreB(8x64) @ Wo + bo
  s8v wof[8];
  {
    const s8v* Wop = (const s8v*)W.Wof;
    #pragma unroll
    for (int f = 0; f < 8; f++) wof[f] = Wop[f*64 + l];
  }
  s8v ef0 = *(const s8v*)&PreBw[(cl & (TPW-1))*SPD + q*8];
  s8v ef1 = *(const s8v*)&PreBw[(cl & (TPW-1))*SPD + 32 + q*8];
  #pragma unroll
  for (int nt = 0; nt < 4; nt++){
    float bn = P.bo[nt*16 + cl];
    f4v ci = { bn, bn, bn, bn };
    f4v oc = __builtin_amdgcn_mfma_f32_16x16x32_bf16(ef0, wof[2*nt+0], ci, 0, 0, 0);
    oc = __builtin_amdgcn_mfma_f32_16x16x32_bf16(ef1, wof[2*nt+1], oc, 0, 0, 0);
    #pragma unroll
    for (int r = 0; r < 4; r++){
      int ro = q*4 + r;
      int rg = i0 + ro;
      if (ro < TPW && rg < P.N) P.out[(size_t)rg*64 + nt*16 + cl] = oc[r];
    }
  }
}

extern "C" void kernel_launch(void* const* d_in, const int* in_sizes, int n_in,
                              void* d_out, int out_size, void* d_ws, size_t ws_size,
                              hipStream_t stream){
  InP P;
  P.points   = (const float*)d_in[0];
  P.features = (const float*)d_in[1];
  P.gidx     = (const int*)d_in[2];
  P.Wq  = (const float*)d_in[3];  P.bq  = (const float*)d_in[4];
  P.Wk  = (const float*)d_in[5];  P.bk  = (const float*)d_in[6];
  P.Wv  = (const float*)d_in[7];  P.bv  = (const float*)d_in[8];
  P.Wp  = (const float*)d_in[9];  P.b_p = (const float*)d_in[10];
  P.bnp_g = (const float*)d_in[11]; P.bnp_b = (const float*)d_in[12];
  P.bnp_m = (const float*)d_in[13]; P.bnp_v = (const float*)d_in[14];
  P.Wg1 = (const float*)d_in[15]; P.bg1 = (const float*)d_in[16];
  P.bng_g = (const float*)d_in[17]; P.bng_b = (const float*)d_in[18];
  P.bng_m = (const float*)d_in[19]; P.bng_v = (const float*)d_in[20];
  P.Wg2 = (const float*)d_in[21]; P.bg2 = (const float*)d_in[22];
  P.Wo  = (const float*)d_in[23]; P.bo  = (const float*)d_in[24];
  P.out = (float*)d_out;
  const int N = in_sizes[0] / 3;
  P.N = N;

  WS W;
  char* w = (char*)d_ws;
  W.qW1 = (unsigned short*)w; w += (size_t)N*64*2;
  W.kvT = (unsigned short*)w; w += (size_t)N*128*2;
  W.WAf = (unsigned short*)w; w += 8*64*8*2;
  W.Wkf = (unsigned short*)w; w += 8*64*8*2;
  W.Wvf = (unsigned short*)w; w += 8*64*8*2;
  W.W1f = (unsigned short*)w; w += 8*64*8*2;
  W.W2f = (unsigned short*)w; w += 8*64*8*2;
  W.Wof = (unsigned short*)w; w += 8*64*8*2;
  W.Wpf = (unsigned short*)w; w += 4*64*8*2;
  W.bq1F = (float*)w; w += 256;
  W.bpF  = (float*)w; w += 256;
  W.bk1F = (float*)w; w += 256;

  const int TILES16 = (N + 15) / 16;
  const int grid16 = (TILES16 + TW - 1) / TW;
  const int TILESM = (N + TPW - 1) / TPW;
  const int gridM = (TILESM + TW - 1) / TW;
  hipLaunchKernelGGL(prep_kernel, dim3(16),     dim3(256), 0, stream, P, W);
  hipLaunchKernelGGL(qkv_kernel,  dim3(grid16), dim3(256), 0, stream, P, W);
  hipLaunchKernelGGL(main_kernel, dim3(gridM),  dim3(256), 0, stream, P, W);
}

// Round 11
// 195.741 us; speedup vs baseline: 1.0344x; 1.0344x over previous
//
#include <hip/hip_runtime.h>
#include <hip/hip_bf16.h>

#define EPSV 1e-5f
#define TW 4    // waves per block
#define TPW 8   // points per wave-tile
#define SPD 76  // padded LDS row stride (shorts)
#define WPD 68  // padded prep LDS row stride (floats; 16B-aligned, conflict-free)

typedef __attribute__((ext_vector_type(8))) short s8v;
typedef __attribute__((ext_vector_type(8))) unsigned short u8v;
typedef __attribute__((ext_vector_type(4))) unsigned short u4v;
typedef __attribute__((ext_vector_type(4))) float f4v;

struct InP {
  const float *points, *features; const int* gidx;
  const float *Wq,*bq,*Wk,*bk,*Wv,*bv,*Wp,*b_p;
  const float *bnp_g,*bnp_b,*bnp_m,*bnp_v;
  const float *Wg1,*bg1,*bng_g,*bng_b,*bng_m,*bng_v;
  const float *Wg2,*bg2,*Wo,*bo;
  float* out; int N;
};
// Workspace layouts (R14 -- PERMUTED so MFMA C-frags store wide and the
// main gather loads wide; producer/consumer co-designed):
//   qW1: N rows x 64 shorts; element (row, col=nt*16+cl) at row*64 + cl*4 + nt
//   kvT: N rows x 128 shorts; kW1 elem (row, nt*16+cl) at row*128 + cl*8 + nt
//        v elem (row, nt*16+cl) at row*128 + cl*8 + 4 + nt
struct WS {
  unsigned short *qW1;                               // N x 64 bf16 (q@W1F + b1F), permuted
  unsigned short *kvT;                               // N x 128 bf16 (kW1|v interleaved), permuted
  unsigned short *WAf, *Wkf, *Wvf, *W1f, *W2f, *Wof; // 8 frags x 64 lanes x 8 bf16
  unsigned short *Wpf;                               // 4 frags x 64 x 8
  float *bq1F, *bpF, *bk1F;                          // 64 fp32 each
};

__device__ __forceinline__ unsigned short f2bf(float x){
  __hip_bfloat16 h = __float2bfloat16(x);
  unsigned short u; __builtin_memcpy(&u, &h, 2); return u;
}
__device__ __forceinline__ float bf2f(unsigned short s){
  union{unsigned u; float f;} c; c.u = ((unsigned)s) << 16; return c.f;
}
__device__ __forceinline__ unsigned pk2(float x, float y){
  __hip_bfloat162 h = __float22bfloat162_rn(make_float2(x, y));
  unsigned u; __builtin_memcpy(&u, &h, 4); return u;
}
__device__ __forceinline__ s8v pack8(f4v x0, f4v x1){
  s8v r;
  ((unsigned*)&r)[0] = pk2(x0[0], x0[1]);
  ((unsigned*)&r)[1] = pk2(x0[2], x0[3]);
  ((unsigned*)&r)[2] = pk2(x1[0], x1[1]);
  ((unsigned*)&r)[3] = pk2(x1[2], x1[3]);
  return r;
}

// ---------------- prep: BN folds + fused k@W1 + B-fragment swizzles -------
// R19: Wg1/Wq/Wk staged in LDS (padded WPD) -- dots run at LDS latency.
__global__ void __launch_bounds__(256) prep_kernel(InP P, WS W){
  __shared__ __align__(16) float sWg1[64*WPD];
  __shared__ __align__(16) float sWq [64*WPD];
  __shared__ __align__(16) float sWk [64*WPD];
  const int tid = threadIdx.x;
  {
    int r = tid >> 2, c0 = (tid & 3) * 16;   // 4 threads per 64-float row
    const f4v* g1 = (const f4v*)(P.Wg1 + r*64 + c0);
    const f4v* gq = (const f4v*)(P.Wq  + r*64 + c0);
    const f4v* gk = (const f4v*)(P.Wk  + r*64 + c0);
    f4v* d1 = (f4v*)(sWg1 + r*WPD + c0);
    f4v* dq = (f4v*)(sWq  + r*WPD + c0);
    f4v* dk = (f4v*)(sWk  + r*WPD + c0);
    #pragma unroll
    for (int u = 0; u < 4; u++){ d1[u] = g1[u]; dq[u] = gq[u]; dk[u] = gk[u]; }
  }
  __syncthreads();

  const int g = blockIdx.x*256 + tid;           // 0..4095
  const int e = g >> 3, j = g & 7;              // e < 512
  const int f = e >> 6, L = e & 63;
  const int ks = f & 1, nt = f >> 1;
  const int n = nt*16 + (L & 15);
  const int k = ks*32 + ((L >> 4) << 3) + j;
  const float sg = P.bng_g[n] * rsqrtf(P.bng_v[n] + EPSV);
  W.W1f[e*8+j] = f2bf(sWg1[k*WPD+n] * sg);
  W.W2f[e*8+j] = f2bf(P.Wg2[k*64+n]);
  W.Wof[e*8+j] = f2bf(P.Wo [k*64+n]);
  W.Wvf[e*8+j] = f2bf(P.Wv [k*64+n]);
  float acc = 0.f, acck = 0.f;
  #pragma unroll 8
  for (int d = 0; d < 64; d++){
    float w1 = sWg1[d*WPD+n];
    acc  += sWq[k*WPD+d] * w1;
    acck += sWk[k*WPD+d] * w1;
  }
  W.WAf[e*8+j] = f2bf(acc  * sg);   // Wq@W1F (BN-scaled)
  W.Wkf[e*8+j] = f2bf(acck * sg);   // Wk@W1F (BN-scaled) -- fused
  if (g < 2048){
    int ep = g >> 3;  // 0..255
    int ntp = ep >> 6, Lp = ep & 63;
    int np_ = ntp*16 + (Lp & 15);
    int kp = ((Lp >> 4) << 3) + j;
    float sp = P.bnp_g[np_] * rsqrtf(P.bnp_v[np_] + EPSV);
    W.Wpf[ep*8+j] = f2bf(kp < 3 ? P.Wp[kp*64+np_]*sp : 0.f);
  }
  if (g < 64){
    float sgt = P.bng_g[g] * rsqrtf(P.bng_v[g] + EPSV);
    float spt = P.bnp_g[g] * rsqrtf(P.bnp_v[g] + EPSV);
    float acc2 = 0.f, acck2 = 0.f;
    for (int d = 0; d < 64; d++){
      float w1 = sWg1[d*WPD+g];
      acc2  += P.bq[d] * w1;
      acck2 += P.bk[d] * w1;
    }
    // qW1 bias carries ALL of b1F (bg1 + BN offset); kW1 bias only bk@W1F
    W.bq1F[g] = acc2*sgt + P.bg1[g]*sgt + P.bng_b[g] - P.bng_m[g]*sgt;
    W.bk1F[g] = acck2*sgt;
    W.bpF[g]  = P.b_p[g]*spt + P.bnp_b[g] - P.bnp_m[g]*spt;
  }
}

// ---- qkv: qW1 = f@(Wq@W1F)+bq1F ; kvT = [f@(Wk@W1F)+bk1F | f@Wv+bv] ----
// R14: holds all three C-mats in regs and stores per row ONE 8B (qW1) +
// ONE 16B (kvT k|v) wide store -- coalesced, 256B contiguous per 16 lanes.
__global__ void __launch_bounds__(256) qkv_kernel(InP P, WS W){
  const int tid = threadIdx.x;
  const int wid = tid >> 6, l = tid & 63;
  const int cl = l & 15, q = l >> 4;
  const int TILES = (P.N + 15) >> 4;
  const int task = blockIdx.x * TW + wid;
  if (task >= TILES) return;
  const int i0 = task * 16;
  int row = i0 + cl; if (row > P.N - 1) row = P.N - 1;
  const float* fr = P.features + (size_t)row*64 + q*8;
  f4v x0 = *(const f4v*)fr;
  f4v x1 = *(const f4v*)(fr + 4);
  s8v fa0 = pack8(x0, x1);
  x0 = *(const f4v*)(fr + 32);
  x1 = *(const f4v*)(fr + 36);
  s8v fa1 = pack8(x0, x1);

  auto comp = [&](const unsigned short* Bf_, const float* biasPtr, f4v* c){
    const s8v* Bf = (const s8v*)Bf_;
    #pragma unroll
    for (int nt = 0; nt < 4; nt++){
      float bn = biasPtr[nt*16 + cl];
      f4v ci = { bn, bn, bn, bn };
      c[nt] = __builtin_amdgcn_mfma_f32_16x16x32_bf16(fa0, Bf[(2*nt+0)*64 + l], ci, 0, 0, 0);
      c[nt] = __builtin_amdgcn_mfma_f32_16x16x32_bf16(fa1, Bf[(2*nt+1)*64 + l], c[nt], 0, 0, 0);
    }
  };
  f4v qc[4], kc[4], vc[4];
  comp(W.WAf, W.bq1F, qc);
  comp(W.Wkf, W.bk1F, kc);
  comp(W.Wvf, P.bv,   vc);

  #pragma unroll
  for (int r = 0; r < 4; r++){
    int rg = i0 + q*4 + r;
    if (rg < P.N){
      u4v qv;
      qv[0] = f2bf(qc[0][r]); qv[1] = f2bf(qc[1][r]);
      qv[2] = f2bf(qc[2][r]); qv[3] = f2bf(qc[3][r]);
      *(u4v*)(W.qW1 + (size_t)rg*64 + cl*4) = qv;
      u8v kv;
      kv[0] = f2bf(kc[0][r]); kv[1] = f2bf(kc[1][r]);
      kv[2] = f2bf(kc[2][r]); kv[3] = f2bf(kc[3][r]);
      kv[4] = f2bf(vc[0][r]); kv[5] = f2bf(vc[1][r]);
      kv[6] = f2bf(vc[2][r]); kv[7] = f2bf(vc[3][r]);
      *(u8v*)(W.kvT + (size_t)rg*128 + cl*8) = kv;
    }
  }
}

// ---------------- main: 8-pt tiles, fused k@W1 C-init, parity-dbuf Sp -----
// (R5/R9 verbatim -- best known-good: main 78.5us, total 197.7us.)
// STRUCTURAL FLOOR (R11-R20 evidence): 204.8MB of uniformly-random 256B
// kvT row gathers, ~58% L2-hit -> 86MB L2-miss at ~1.1 TB/s random-granule
// rate = ~78us. Time tracks gather traffic ONLY (R7: +32% fetch -> +15%
// time; R2: +12.5% instrs -> +5%). Exonerated: gather shape (R3/R4),
// issue-time (R2), depth (R6), occupancy (R1/R5: 17->28% flat), forced
// bounds (R11: spills), nt hints (R7: worse), fusion (R8: coop launch
// incompatible), chain ILP (R10: gain == residency loss). Traffic is
// irreducible: each row consumed in full once, indices random, bf16
// required by absmax. Non-main residue ~119us = harness reset dispatches.
__global__ void __launch_bounds__(256, 2) main_kernel(InP P, WS W){
  __shared__ __align__(16) unsigned short Sp[TW][2][16*SPD];
  __shared__ __align__(16) unsigned short PreB[TW][TPW*SPD];
  __shared__ __align__(16) int sI[TW][TPW*16];
  __shared__ __align__(16) unsigned short sW1[8*64*8];
  __shared__ __align__(16) unsigned short sW2[8*64*8];
  const int tid = threadIdx.x;
  const int wid = tid >> 6, l = tid & 63;
  const int cl = l & 15, q = l >> 4;
  const int TILES = (P.N + TPW - 1) / TPW;
  const int task = blockIdx.x * TW + wid;

  // cooperative W1F/W2F staging: 2 x 8KB, 256 threads x int4 x 2 each.
  // Must complete before any early return (barrier + exited waves is UB).
  {
    const int4* s1 = (const int4*)W.W1f;
    const int4* s2 = (const int4*)W.W2f;
    ((int4*)sW1)[tid]       = s1[tid];
    ((int4*)sW1)[tid + 256] = s1[tid + 256];
    ((int4*)sW2)[tid]       = s2[tid];
    ((int4*)sW2)[tid + 256] = s2[tid + 256];
  }
  __syncthreads();
  if (task >= TILES) return;
  const int i0 = task * TPW;
  unsigned short* PreBw = PreB[wid];
  int* sIw = sI[wid];
  const s8v* W1s = (const s8v*)sW1;   // frag f, lane l -> W1s[f*64 + l]
  const s8v* W2s = (const s8v*)sW2;

  // cooperative neighbor-index stage (TPW*16 = 128 ints per tile, 2/lane)
  {
    long base = (long)i0*16 + l*2;
    long maxb = (long)P.N*16 - 2;
    if (base > maxb) base = maxb;
    int2 gi = *(const int2*)(P.gidx + base);
    *(int2*)&sIw[l*2] = gi;
  }

  // held B-frags: Wp only (W1/W2 read per-use from block-shared LDS)
  s8v wpf[4];
  {
    const s8v* Wpp = (const s8v*)W.Wpf;
    #pragma unroll
    for (int f = 0; f < 4; f++) wpf[f] = Wpp[f*64 + l];
  }
  float bp4[4], b24[4];
  #pragma unroll
  for (int nt = 0; nt < 4; nt++){ bp4[nt] = W.bpF[nt*16 + cl]; b24[nt] = P.bg2[nt*16 + cl]; }

  // ---- prologue prefetch for pt = 0 (neighbor xyz, center, qW1 row)
  float ngx=0.f, ngy=0.f, ngz=0.f;
  {
    int nidx = sIw[cl];
    if (l < 16){ const float* gp = P.points + (size_t)nidx*3; ngx=gp[0]; ngy=gp[1]; ngz=gp[2]; }
  }
  float ncx = P.points[(size_t)i0*3+0];
  float ncy = P.points[(size_t)i0*3+1];
  float ncz = P.points[(size_t)i0*3+2];
  float nq0, nq1, nq2, nq3;
  {
    u4v qv = *(const u4v*)(W.qW1 + (size_t)i0*64 + cl*4);
    nq0 = bf2f(qv[0]); nq1 = bf2f(qv[1]); nq2 = bf2f(qv[2]); nq3 = bf2f(qv[3]);
  }

  int zro = 0;  // opaque zero (defeats LICM of the sW1/sW2 frag reads)

  #pragma unroll 2
  for (int pt = 0; pt < TPW; pt++){
    asm volatile("" : "+v"(zro));   // loop-variant zero
    unsigned short* Spw = Sp[wid][pt & 1];
    // rotate prefetch -> current
    float gx=ngx, gy=ngy, gz=ngz, cx=ncx, cy=ncy, cz=ncz;
    float qcn4[4] = { nq0, nq1, nq2, nq3 };
    const bool valid = (i0 + pt < P.N);

    // 1. gather kw|vv rows for CURRENT point: per lane 4 x 16B loads;
    //    shorts 0-3 = kW1 cols {0,16,32,48}+cl, shorts 4-7 = v cols.
    u8v kv8[4];
    {
      int4 vidx = *(const int4*)&sIw[pt*16 + q*4];
      #pragma unroll
      for (int r = 0; r < 4; r++)
        kv8[r] = *(const u8v*)(W.kvT + (size_t)vidx[r]*128 + cl*8);
    }

    // 2. p = relu(rel @ WpF + bpF), write to Sp (C-layout, bf16 scalar)
    s8v ap;
    ((unsigned*)&ap)[0] = pk2(gx-cx, gy-cy);
    ((unsigned*)&ap)[1] = pk2(gz-cz, 0.f);
    ((unsigned*)&ap)[2] = 0u; ((unsigned*)&ap)[3] = 0u;
    f4v pc[4];
    #pragma unroll
    for (int nt = 0; nt < 4; nt++){
      f4v ci = { bp4[nt], bp4[nt], bp4[nt], bp4[nt] };
      pc[nt] = __builtin_amdgcn_mfma_f32_16x16x32_bf16(ap, wpf[nt], ci, 0, 0, 0);
    }
    #pragma unroll
    for (int nt = 0; nt < 4; nt++){
      #pragma unroll
      for (int r = 0; r < 4; r++){
        pc[nt][r] = fmaxf(pc[nt][r], 0.f);
        Spw[(q*4+r)*SPD + nt*16 + cl] = f2bf(pc[nt][r]);
      }
    }

    // 3. prefetch pt+1 xyz / center / qW1 (wraps harmlessly at pt=TPW-1)
    {
      int np = (pt + 1) & (TPW-1);
      int nidx = sIw[np*16 + cl];
      if (l < 16){ const float* gp = P.points + (size_t)nidx*3; ngx=gp[0]; ngy=gp[1]; ngz=gp[2]; }
      int ii = i0 + np; if (ii > P.N - 1) ii = P.N - 1;
      ncx = P.points[(size_t)ii*3+0];
      ncy = P.points[(size_t)ii*3+1];
      ncz = P.points[(size_t)ii*3+2];
      u4v qv = *(const u4v*)(W.qW1 + (size_t)ii*64 + cl*4);
      nq0 = bf2f(qv[0]); nq1 = bf2f(qv[1]); nq2 = bf2f(qv[2]); nq3 = bf2f(qv[3]);
    }

    // 4. read p back as A-frags (no subtraction -- k@W1 folded into C-init)
    s8v af0 = *(const s8v*)&Spw[cl*SPD + q*8];
    s8v af1 = *(const s8v*)&Spw[cl*SPD + 32 + q*8];

    // 5. T = relu(p @ W1F + (qW1row - kW1row)); W1F frags from shared LDS
    f4v tc[4];
    #pragma unroll
    for (int nt = 0; nt < 4; nt++){
      f4v ci = { qcn4[nt] - bf2f((unsigned short)kv8[0][nt]),
                 qcn4[nt] - bf2f((unsigned short)kv8[1][nt]),
                 qcn4[nt] - bf2f((unsigned short)kv8[2][nt]),
                 qcn4[nt] - bf2f((unsigned short)kv8[3][nt]) };
      s8v b0 = W1s[(2*nt+0)*64 + l + zro];
      s8v b1 = W1s[(2*nt+1)*64 + l + zro];
      tc[nt] = __builtin_amdgcn_mfma_f32_16x16x32_bf16(af0, b0, ci, 0, 0, 0);
      tc[nt] = __builtin_amdgcn_mfma_f32_16x16x32_bf16(af1, b1, tc[nt], 0, 0, 0);
      #pragma unroll
      for (int r = 0; r < 4; r++) tc[nt][r] = fmaxf(tc[nt][r], 0.f);
    }

    // 6. T -> Sp (bf16 scalar C-write), read back directly as A-frags
    #pragma unroll
    for (int nt = 0; nt < 4; nt++)
      #pragma unroll
      for (int r = 0; r < 4; r++)
        Spw[(q*4+r)*SPD + nt*16 + cl] = f2bf(tc[nt][r]);
    s8v tf0 = *(const s8v*)&Spw[cl*SPD + q*8];
    s8v tf1 = *(const s8v*)&Spw[cl*SPD + 32 + q*8];

    // 7. H = T @ W2 + b2; W2 frags from shared LDS
    f4v hc[4];
    #pragma unroll
    for (int nt = 0; nt < 4; nt++){
      f4v ci = { b24[nt], b24[nt], b24[nt], b24[nt] };
      s8v b0 = W2s[(2*nt+0)*64 + l + zro];
      s8v b1 = W2s[(2*nt+1)*64 + l + zro];
      hc[nt] = __builtin_amdgcn_mfma_f32_16x16x32_bf16(tf0, b0, ci, 0, 0, 0);
      hc[nt] = __builtin_amdgcn_mfma_f32_16x16x32_bf16(tf1, b1, hc[nt], 0, 0, 0);
    }

    // 8. softmax over 16 neighbor rows (no max-shift: |h| small, exp safe)
    //    + weighted sum of (v+p); vv shorts 4-7 of kv8[r]
    float pre4[4];
    #pragma unroll
    for (int nt = 0; nt < 4; nt++){
      float s = 0.f, acc = 0.f;
      #pragma unroll
      for (int r = 0; r < 4; r++){
        float e2 = __expf(hc[nt][r]);
        s += e2;
        acc = fmaf(e2, bf2f((unsigned short)kv8[r][4+nt]) + pc[nt][r], acc);
      }
      s += __shfl_xor(s, 16, 64);
      s += __shfl_xor(s, 32, 64);
      acc += __shfl_xor(acc, 16, 64);
      acc += __shfl_xor(acc, 32, 64);
      pre4[nt] = acc * __builtin_amdgcn_rcpf(s);
    }
    if (valid){
      float sa = (l & 16) ? pre4[1] : pre4[0];
      float sb = (l & 16) ? pre4[3] : pre4[2];
      PreBw[pt*SPD + l] = f2bf((l & 32) ? sb : sa);
    }
  }

  // inline epilogue: out rows = PreB(8x64) @ Wo + bo (rows 8..15 duplicated,
  // discarded by the store guard)
  s8v wof[8];
  {
    const s8v* Wop = (const s8v*)W.Wof;
    #pragma unroll
    for (int f = 0; f < 8; f++) wof[f] = Wop[f*64 + l];
  }
  s8v ef0 = *(const s8v*)&PreBw[(cl & (TPW-1))*SPD + q*8];
  s8v ef1 = *(const s8v*)&PreBw[(cl & (TPW-1))*SPD + 32 + q*8];
  #pragma unroll
  for (int nt = 0; nt < 4; nt++){
    float bn = P.bo[nt*16 + cl];
    f4v ci = { bn, bn, bn, bn };
    f4v oc = __builtin_amdgcn_mfma_f32_16x16x32_bf16(ef0, wof[2*nt+0], ci, 0, 0, 0);
    oc = __builtin_amdgcn_mfma_f32_16x16x32_bf16(ef1, wof[2*nt+1], oc, 0, 0, 0);
    #pragma unroll
    for (int r = 0; r < 4; r++){
      int ro = q*4 + r;
      int rg = i0 + ro;
      if (ro < TPW && rg < P.N) P.out[(size_t)rg*64 + nt*16 + cl] = oc[r];
    }
  }
}

extern "C" void kernel_launch(void* const* d_in, const int* in_sizes, int n_in,
                              void* d_out, int out_size, void* d_ws, size_t ws_size,
                              hipStream_t stream){
  InP P;
  P.points   = (const float*)d_in[0];
  P.features = (const float*)d_in[1];
  P.gidx     = (const int*)d_in[2];
  P.Wq  = (const float*)d_in[3];  P.bq  = (const float*)d_in[4];
  P.Wk  = (const float*)d_in[5];  P.bk  = (const float*)d_in[6];
  P.Wv  = (const float*)d_in[7];  P.bv  = (const float*)d_in[8];
  P.Wp  = (const float*)d_in[9];  P.b_p = (const float*)d_in[10];
  P.bnp_g = (const float*)d_in[11]; P.bnp_b = (const float*)d_in[12];
  P.bnp_m = (const float*)d_in[13]; P.bnp_v = (const float*)d_in[14];
  P.Wg1 = (const float*)d_in[15]; P.bg1 = (const float*)d_in[16];
  P.bng_g = (const float*)d_in[17]; P.bng_b = (const float*)d_in[18];
  P.bng_m = (const float*)d_in[19]; P.bng_v = (const float*)d_in[20];
  P.Wg2 = (const float*)d_in[21]; P.bg2 = (const float*)d_in[22];
  P.Wo  = (const float*)d_in[23]; P.bo  = (const float*)d_in[24];
  P.out = (float*)d_out;
  const int N = in_sizes[0] / 3;
  P.N = N;

  WS W;
  char* w = (char*)d_ws;
  W.qW1 = (unsigned short*)w; w += (size_t)N*64*2;
  W.kvT = (unsigned short*)w; w += (size_t)N*128*2;
  W.WAf = (unsigned short*)w; w += 8*64*8*2;
  W.Wkf = (unsigned short*)w; w += 8*64*8*2;
  W.Wvf = (unsigned short*)w; w += 8*64*8*2;
  W.W1f = (unsigned short*)w; w += 8*64*8*2;
  W.W2f = (unsigned short*)w; w += 8*64*8*2;
  W.Wof = (unsigned short*)w; w += 8*64*8*2;
  W.Wpf = (unsigned short*)w; w += 4*64*8*2;
  W.bq1F = (float*)w; w += 256;
  W.bpF  = (float*)w; w += 256;
  W.bk1F = (float*)w; w += 256;

  const int TILES16 = (N + 15) / 16;
  const int grid16 = (TILES16 + TW - 1) / TW;
  const int TILESM = (N + TPW - 1) / TPW;
  const int gridM = (TILESM + TW - 1) / TW;
  hipLaunchKernelGGL(prep_kernel, dim3(16),     dim3(256), 0, stream, P, W);
  hipLaunchKernelGGL(qkv_kernel,  dim3(grid16), dim3(256), 0, stream, P, W);
  hipLaunchKernelGGL(main_kernel, dim3(gridM),  dim3(256), 0, stream, P, W);
}